// Round 4
// baseline (3217.168 us; speedup 1.0000x reference)
//
#include <hip/hip_runtime.h>
#include <math.h>

#define NPTS 256
#define NSRC 1024
#define NITER 100
#define KCONV 577.0780163555854f         // log2(e)/eps
#define INV_KC 0.0017328679513998632f    // eps*ln2
#define EPS_LBC (-0.013862943611198906f) // eps*ln(1/256)
#define EPSQ 0.0025f
#define NEG_BIG (-1e30f)

#define EXP2F(x) __builtin_amdgcn_exp2f(x)
#define LOG2F(x) __builtin_amdgcn_logf(x)
#define F4E(v,e) ((e)==0?(v).x:(e)==1?(v).y:(e)==2?(v).z:(v).w)

__global__ __launch_bounds__(1024)
void ot_sinkhorn(const float* __restrict__ dens_all,
                 const float* __restrict__ pts_all,
                 float* __restrict__ partials)
{
  __shared__ __align__(16) float F_L[32 * 36];   // ab F tile, padded stride 36 (2-way max)
  __shared__ __align__(16) float G_L[NPTS];      // ab g potentials
  __shared__ __align__(16) float pxL[NPTS];
  __shared__ __align__(16) float pyL[NPTS];
  __shared__ __align__(16) float epslaL[NSRC];
  __shared__ __align__(16) float aL[NSRC];
  __shared__ __align__(16) float FaL[NSRC];      // aa potentials
  __shared__ __align__(16) float TaL[33 * 32];   // aa separable intermediate
  __shared__ __align__(16) float Fb[NPTS];       // bb potentials
  __shared__ __align__(16) float Gb[NPTS];
  __shared__ float red[16];

  const int tid = threadIdx.x;
  const int bid = blockIdx.x;
  const int type = bid >> 3;           // 0=ab 1=bb 2=aa
  const int img = bid & 7;
  const float* dens = dens_all + img * NSRC;
  const float* pts = pts_all + img * (NPTS * 2);

  float acc = 0.0f;

  if (type == 0) {
    // ======================= ot_ab : one block, no global sync =======================
    {
      float a = dens[tid];
      aL[tid] = a;
      float ela = (a > 0.0f) ? EPSQ * __logf(a) : NEG_BIG;
      epslaL[tid] = ela;
      F_L[(tid >> 5) * 36 + (tid & 31)] = ela;   // f = 0
      if (tid < NPTS) { pxL[tid] = pts[2 * tid]; pyL[tid] = pts[2 * tid + 1]; }
    }
    __syncthreads();

    // g-half geometry: one wave per target, 16 targets per wave
    const int w = tid >> 6, lane = tid & 63;
    const int r = lane & 31, h = lane >> 5;
    const float ry = (float)(r * 8 + 4);
    const float xbase = (float)(h * 128 + 4);

    // f-half geometry: 16 lanes per cell, 16 passes of 64 cells
    const int cl = tid >> 4, ch = tid & 15;
    const float cx = (float)((cl & 31) * 8 + 4);
    const float cy0 = (float)((cl >> 5) * 8 + 4);
    float4 px4[4], py4[4];
    #pragma unroll
    for (int k = 0; k < 4; ++k) {
      px4[k] = *(const float4*)(pxL + ch * 16 + k * 4);
      py4[k] = *(const float4*)(pyL + ch * 16 + k * 4);
    }
    const float4* F_L4 = (const float4*)F_L;
    const float4* G_L4 = (const float4*)G_L;

    float tt[16];
    for (int it = 0;; ++it) {
      // ---- g-half: per wave, 16 targets, F fragment hoisted ----
      float4 Fv[4];
      #pragma unroll
      for (int k = 0; k < 4; ++k) Fv[k] = F_L4[r * 9 + h * 4 + k];

      #pragma unroll 1
      for (int t = 0; t < 16; ++t) {
        const int j = w * 16 + t;
        const float pxj = pxL[j], pyj = pyL[j];
        const float dy = ry - pyj;
        const float dy2 = dy * dy;
        const float px0 = xbase - pxj;
        float m = -INFINITY;
        #pragma unroll
        for (int k = 0; k < 4; ++k) {
          #pragma unroll
          for (int e = 0; e < 4; ++e) {
            float dx = px0 + (float)(k * 32 + e * 8);
            float v = fmaf(fmaf(dx, dx, dy2), -0.5f, F4E(Fv[k], e));
            tt[k * 4 + e] = v;
            m = fmaxf(m, v);
          }
        }
        #pragma unroll
        for (int o = 1; o < 64; o <<= 1) m = fmaxf(m, __shfl_xor(m, o, 64));
        const float mk = m * KCONV;
        float s = 0.0f;
        #pragma unroll
        for (int i = 0; i < 16; ++i) s += EXP2F(fmaf(tt[i], KCONV, -mk));
        #pragma unroll
        for (int o = 1; o < 64; o <<= 1) s += __shfl_xor(s, o, 64);
        const float g = -(m + LOG2F(s) * INV_KC);
        if (it == NITER) {
          if (lane == 0) acc += g * (1.0f / 256.0f);
        } else if (lane == 0) {
          G_L[j] = g + EPS_LBC;
        }
      }
      if (it == NITER) break;
      __syncthreads();

      // ---- f-half: 16 passes, G slice cached in registers ----
      float4 G4[4];
      #pragma unroll
      for (int k = 0; k < 4; ++k) G4[k] = G_L4[ch * 4 + k];
      #pragma unroll 1
      for (int p = 0; p < 16; ++p) {
        const int c = p * 64 + cl;
        const float cy = cy0 + (float)(p * 16);
        float m = -INFINITY;
        #pragma unroll
        for (int k = 0; k < 4; ++k) {
          #pragma unroll
          for (int e = 0; e < 4; ++e) {
            float dx = F4E(px4[k], e) - cx;
            float dyq = F4E(py4[k], e) - cy;
            float u = fmaf(dyq, dyq, dx * dx);
            float v = fmaf(u, -0.5f, F4E(G4[k], e));
            tt[k * 4 + e] = v;
            m = fmaxf(m, v);
          }
        }
        #pragma unroll
        for (int o = 1; o < 16; o <<= 1) m = fmaxf(m, __shfl_xor(m, o, 64));
        const float mk = m * KCONV;
        float s = 0.0f;
        #pragma unroll
        for (int i = 0; i < 16; ++i) s += EXP2F(fmaf(tt[i], KCONV, -mk));
        #pragma unroll
        for (int o = 1; o < 16; o <<= 1) s += __shfl_xor(s, o, 64);
        if (ch == 0) {
          const float f = -(m + LOG2F(s) * INV_KC);
          F_L[(c >> 5) * 36 + (c & 31)] = f + epslaL[c];
          if (it == NITER - 1) acc += aL[c] * f;
        }
      }
      __syncthreads();
    }
  } else if (type == 1) {
    // ======================= ot_bb : one block =======================
    if (tid < NPTS) {
      pxL[tid] = pts[2 * tid];
      pyL[tid] = pts[2 * tid + 1];
      Fb[tid] = EPS_LBC;                  // f = 0
    }
    __syncthreads();

    const int cl = tid >> 4, ch = tid & 15;
    float4 px4[4], py4[4];
    #pragma unroll
    for (int k = 0; k < 4; ++k) {
      px4[k] = *(const float4*)(pxL + ch * 16 + k * 4);
      py4[k] = *(const float4*)(pyL + ch * 16 + k * 4);
    }
    const float4* Fb4 = (const float4*)Fb;
    const float4* Gb4 = (const float4*)Gb;

    float tt[16];
    for (int it = 0;; ++it) {
      // ---- g-half ----
      float4 A4[4];
      #pragma unroll
      for (int k = 0; k < 4; ++k) A4[k] = Fb4[ch * 4 + k];
      #pragma unroll 1
      for (int p = 0; p < 4; ++p) {
        const int tj = p * 64 + cl;
        const float qx = pxL[tj], qy = pyL[tj];
        float m = -INFINITY;
        #pragma unroll
        for (int k = 0; k < 4; ++k) {
          #pragma unroll
          for (int e = 0; e < 4; ++e) {
            float dx = F4E(px4[k], e) - qx;
            float dyq = F4E(py4[k], e) - qy;
            float u = fmaf(dyq, dyq, dx * dx);
            float v = fmaf(u, -0.5f, F4E(A4[k], e));
            tt[k * 4 + e] = v;
            m = fmaxf(m, v);
          }
        }
        #pragma unroll
        for (int o = 1; o < 16; o <<= 1) m = fmaxf(m, __shfl_xor(m, o, 64));
        const float mk = m * KCONV;
        float s = 0.0f;
        #pragma unroll
        for (int i = 0; i < 16; ++i) s += EXP2F(fmaf(tt[i], KCONV, -mk));
        #pragma unroll
        for (int o = 1; o < 16; o <<= 1) s += __shfl_xor(s, o, 64);
        const float g = -(m + LOG2F(s) * INV_KC);
        if (it == NITER) {
          if (ch == 0) acc += g * (1.0f / 256.0f);
        } else if (ch == 0) {
          Gb[tj] = g + EPS_LBC;
        }
      }
      if (it == NITER) break;
      __syncthreads();

      // ---- f-half (symmetric) ----
      float4 B4[4];
      #pragma unroll
      for (int k = 0; k < 4; ++k) B4[k] = Gb4[ch * 4 + k];
      #pragma unroll 1
      for (int p = 0; p < 4; ++p) {
        const int tj = p * 64 + cl;
        const float qx = pxL[tj], qy = pyL[tj];
        float m = -INFINITY;
        #pragma unroll
        for (int k = 0; k < 4; ++k) {
          #pragma unroll
          for (int e = 0; e < 4; ++e) {
            float dx = F4E(px4[k], e) - qx;
            float dyq = F4E(py4[k], e) - qy;
            float u = fmaf(dyq, dyq, dx * dx);
            float v = fmaf(u, -0.5f, F4E(B4[k], e));
            tt[k * 4 + e] = v;
            m = fmaxf(m, v);
          }
        }
        #pragma unroll
        for (int o = 1; o < 16; o <<= 1) m = fmaxf(m, __shfl_xor(m, o, 64));
        const float mk = m * KCONV;
        float s = 0.0f;
        #pragma unroll
        for (int i = 0; i < 16; ++i) s += EXP2F(fmaf(tt[i], KCONV, -mk));
        #pragma unroll
        for (int o = 1; o < 16; o <<= 1) s += __shfl_xor(s, o, 64);
        if (ch == 0) {
          const float f = -(m + LOG2F(s) * INV_KC);
          Fb[tj] = f + EPS_LBC;
          if (it == NITER - 1) acc += f * (1.0f / 256.0f);
        }
      }
      __syncthreads();
    }
  } else {
    // ======================= ot_aa : one block, separable LSE =======================
    {
      float a = dens[tid];
      aL[tid] = a;
      float ela = (a > 0.0f) ? EPSQ * __logf(a) : NEG_BIG;
      epslaL[tid] = ela;
      FaL[tid] = ela;                    // f = 0, cost units
    }
    __syncthreads();

    const int q1 = tid & 31, r1 = tid >> 5;
    const float r1f = (float)r1;
    const int r2 = tid & 31, q2 = tid >> 5;
    const float q2f = (float)q2;
    const int np = r2 * 32 + q2;
    const float a_np = aL[np];
    const float ela_np = epslaL[np];

    float t[32];
    for (int it = 0;; ++it) {
      // ============ g-half ============
      {
        float m = -INFINITY;
        #pragma unroll
        for (int rr = 0; rr < 32; ++rr) {
          float d = (float)rr - r1f;
          float v = fmaf(d * d, -32.0f, FaL[rr * 32 + q1]);
          t[rr] = v; m = fmaxf(m, v);
        }
        float s = 0.0f;
        #pragma unroll
        for (int rr = 0; rr < 32; ++rr) s += EXP2F((t[rr] - m) * KCONV);
        TaL[q1 * 33 + r1] = m + LOG2F(s) * INV_KC;
      }
      __syncthreads();
      float pot;
      {
        float m = -INFINITY;
        #pragma unroll
        for (int qi = 0; qi < 32; ++qi) {
          float d = (float)qi - q2f;
          float v = fmaf(d * d, -32.0f, TaL[qi * 33 + r2]);
          t[qi] = v; m = fmaxf(m, v);
        }
        float s = 0.0f;
        #pragma unroll
        for (int qi = 0; qi < 32; ++qi) s += EXP2F((t[qi] - m) * KCONV);
        pot = -(m + LOG2F(s) * INV_KC);
      }
      if (it == NITER) { acc += a_np * pot; break; }
      FaL[np] = pot + ela_np;            // G side, weights = a
      __syncthreads();

      // ============ f-half ============
      {
        float m = -INFINITY;
        #pragma unroll
        for (int rr = 0; rr < 32; ++rr) {
          float d = (float)rr - r1f;
          float v = fmaf(d * d, -32.0f, FaL[rr * 32 + q1]);
          t[rr] = v; m = fmaxf(m, v);
        }
        float s = 0.0f;
        #pragma unroll
        for (int rr = 0; rr < 32; ++rr) s += EXP2F((t[rr] - m) * KCONV);
        TaL[q1 * 33 + r1] = m + LOG2F(s) * INV_KC;
      }
      __syncthreads();
      {
        float m = -INFINITY;
        #pragma unroll
        for (int qi = 0; qi < 32; ++qi) {
          float d = (float)qi - q2f;
          float v = fmaf(d * d, -32.0f, TaL[qi * 33 + r2]);
          t[qi] = v; m = fmaxf(m, v);
        }
        float s = 0.0f;
        #pragma unroll
        for (int qi = 0; qi < 32; ++qi) s += EXP2F((t[qi] - m) * KCONV);
        pot = -(m + LOG2F(s) * INV_KC);
      }
      if (it == NITER - 1) acc += a_np * pot;
      FaL[np] = pot + ela_np;
      __syncthreads();
    }
  }

  // ---- block reduction + partial write ----
  {
    #pragma unroll
    for (int o = 32; o; o >>= 1) acc += __shfl_xor(acc, o, 64);
    __syncthreads();
    if ((tid & 63) == 0) red[tid >> 6] = acc;
    __syncthreads();
    if (tid == 0) {
      float tsum = 0.0f;
      #pragma unroll
      for (int k = 0; k < 16; ++k) tsum += red[k];
      partials[type * 8 + img] = tsum;
    }
  }
}

__global__ void ot_finalize(const float* __restrict__ partials, float* __restrict__ out) {
  if (threadIdx.x == 0 && blockIdx.x == 0) {
    float t = 0.0f;
    #pragma unroll
    for (int i = 0; i < 8; ++i)
      t += partials[i] - 0.5f * (partials[8 + i] + partials[16 + i]);
    out[0] = t;
  }
}

extern "C" void kernel_launch(void* const* d_in, const int* in_sizes, int n_in,
                              void* d_out, int out_size, void* d_ws, size_t ws_size,
                              hipStream_t stream) {
  const float* dens = (const float*)d_in[0];   // (8,1,32,32) f32
  const float* pts  = (const float*)d_in[1];   // (8,256,2)   f32
  float* partials = (float*)d_ws;              // 24 floats, fully rewritten each launch
  ot_sinkhorn<<<dim3(24), dim3(1024), 0, stream>>>(dens, pts, partials);
  ot_finalize<<<dim3(1), dim3(64), 0, stream>>>(partials, (float*)d_out);
}

// Round 5
// 661.849 us; speedup vs baseline: 4.8609x; 4.8609x over previous
//
#include <hip/hip_runtime.h>
#include <math.h>

#define NPTS 256
#define NSRC 1024
#define NITER 100
#define KCONV 577.0780163555854f         // log2(e)/eps
#define INV_KC 0.0017328679513998632f    // eps*ln2
#define EPS_LBC (-0.013862943611198906f) // eps*ln(1/256)
#define EPSQ 0.0025f
#define NEG_BIG (-1e30f)

#define AB_K 16
#define BB_K 8

// ws layout (32-bit words)
#define WS_ABF 512
#define WS_ABG 8704
#define WS_BBF 10752
#define WS_BBG 12800
#define WS_PART 14848
#define WS_MEMSET_BYTES 2048

#define EXP2F(x) __builtin_amdgcn_exp2f(x)
#define LOG2F(x) __builtin_amdgcn_logf(x)
#define F4E(v,e) ((e)==0?(v).x:(e)==1?(v).y:(e)==2?(v).z:(v).w)

// L3-coherent (agent-scope, relaxed => no L2 writeback/invalidate fences)
__device__ __forceinline__ void st_coh(float* p, float v) {
  __hip_atomic_store((unsigned int*)p, __float_as_uint(v), __ATOMIC_RELAXED, __HIP_MEMORY_SCOPE_AGENT);
}
__device__ __forceinline__ float ld_coh(const float* p) {
  return __uint_as_float(__hip_atomic_load((const unsigned int*)p, __ATOMIC_RELAXED, __HIP_MEMORY_SCOPE_AGENT));
}
__device__ __forceinline__ void flag_signal(unsigned int* flag, unsigned int val) {
  __syncthreads();  // every wave drains its vmem stores (s_waitcnt vmcnt(0)) before barrier release
  if (threadIdx.x == 0)
    __hip_atomic_store(flag, val, __ATOMIC_RELAXED, __HIP_MEMORY_SCOPE_AGENT);
}
__device__ __forceinline__ void flag_waitall(const unsigned int* flags, int K, unsigned int want) {
  const int lane = threadIdx.x & 63;
  const unsigned int* p = flags + ((lane < K) ? lane : 0);
  for (;;) {
    unsigned int v = __hip_atomic_load(p, __ATOMIC_RELAXED, __HIP_MEMORY_SCOPE_AGENT);
    if (__all((lane >= K) || (v >= want))) break;
  }
  asm volatile("" ::: "memory");
}

__global__ __launch_bounds__(1024)
void ot_sinkhorn(const float* __restrict__ dens_all,
                 const float* __restrict__ pts_all,
                 float* __restrict__ ws)
{
  __shared__ __align__(16) float F_L[32 * 36];   // ab F staging (pad 36)
  __shared__ __align__(16) float GcL[16 * 20];   // ab G staging (pad 20)
  __shared__ __align__(16) float pxP[16 * 20];   // ab padded point coords
  __shared__ __align__(16) float pyP[16 * 20];
  __shared__ __align__(16) float pxL[NPTS];
  __shared__ __align__(16) float pyL[NPTS];
  __shared__ __align__(16) float ALb[32 * 12];   // bb staging (12 per 8)
  __shared__ __align__(16) float FaL[NSRC];      // aa potentials
  __shared__ __align__(16) float TaL[32 * 33];   // aa intermediate [q][r]
  __shared__ __align__(16) float PM[16 * 33];    // aa colmax partials
  __shared__ __align__(16) float CM[32];         // aa colmax
  __shared__ float red[16];

  const int tid = threadIdx.x;
  const int bid = blockIdx.x;
  unsigned int* flags = (unsigned int*)ws;
  float* partials = ws + WS_PART;

  float acc = 0.0f;

  if (bid < 128) {
    // =================== ot_ab : 8 teams x 16 blocks ===================
    const int img = bid >> 4, sub = bid & 15;
    const float* dens = dens_all + img * NSRC;
    const float* pts = pts_all + img * (NPTS * 2);
    unsigned int* flg = flags + img * 16;
    float* Fbuf = ws + WS_ABF + img * NSRC;
    float* Gbuf = ws + WS_ABG + img * NPTS;

    if (tid < NPTS) {
      float px = pts[2 * tid], py = pts[2 * tid + 1];
      pxL[tid] = px; pyL[tid] = py;
      pxP[(tid >> 4) * 20 + (tid & 15)] = px;
      pyP[(tid >> 4) * 20 + (tid & 15)] = py;
    }
    __syncthreads();

    // g-half: one wave per target
    const int w = tid >> 6, lane = tid & 63;
    const int r = lane & 31, h = lane >> 5;
    const int j = sub * 16 + w;
    const float pxj = pxL[j], pyj = pyL[j];
    const float dyv = (float)(r * 8 + 4) - pyj;
    const float dy2 = dyv * dyv;
    const float px0 = (float)(h * 128 + 4) - pxj;

    // f-half: 16 lanes per cell, 64 cells per block
    const int cl = tid >> 4, ch = tid & 15;
    const int c = sub * 64 + cl;
    const float cx = (float)((c & 31) * 8 + 4);
    const float cy = (float)((c >> 5) * 8 + 4);
    const float a_c = dens[c];
    const float epsla_c = (a_c > 0.0f) ? EPSQ * __logf(a_c) : NEG_BIG;

    float Freg[16];
    #pragma unroll
    for (int k = 0; k < 4; ++k)
      #pragma unroll
      for (int e = 0; e < 4; ++e) {
        float d0 = dens[r * 32 + h * 16 + k * 4 + e];
        Freg[k * 4 + e] = (d0 > 0.0f) ? EPSQ * __logf(d0) : NEG_BIG;
      }

    const float4* GcL4 = (const float4*)GcL;
    const float4* F_L4 = (const float4*)F_L;
    const float4* pxP4 = (const float4*)pxP;
    const float4* pyP4 = (const float4*)pyP;

    for (int it = 0;; ++it) {
      // ---- g-half ----
      float tt[16];
      float m = -INFINITY;
      #pragma unroll
      for (int i = 0; i < 16; ++i) {
        float dx = px0 + (float)((i >> 2) * 32 + (i & 3) * 8);
        float v = fmaf(fmaf(dx, dx, dy2), -0.5f, Freg[i]);
        tt[i] = v; m = fmaxf(m, v);
      }
      #pragma unroll
      for (int o = 1; o < 64; o <<= 1) m = fmaxf(m, __shfl_xor(m, o, 64));
      const float mk = m * KCONV;
      float s = 0.0f;
      #pragma unroll
      for (int i = 0; i < 16; ++i) s += EXP2F(fmaf(tt[i], KCONV, -mk));
      #pragma unroll
      for (int o = 1; o < 64; o <<= 1) s += __shfl_xor(s, o, 64);
      const float g = -(m + LOG2F(s) * INV_KC);

      if (it == NITER) { if (lane == 0) acc += g * (1.0f / 256.0f); break; }
      if (lane == 0) st_coh(Gbuf + j, g + EPS_LBC);
      flag_signal(flg + sub, 2 * it + 1);
      flag_waitall(flg, AB_K, 2 * it + 1);
      if (tid < NPTS) GcL[(tid >> 4) * 20 + (tid & 15)] = ld_coh(Gbuf + tid);
      __syncthreads();

      // ---- f-half ----
      float mf = -INFINITY;
      #pragma unroll
      for (int k = 0; k < 4; ++k) {
        float4 pxv = pxP4[ch * 5 + k];
        float4 pyv = pyP4[ch * 5 + k];
        float4 Gv  = GcL4[ch * 5 + k];
        #pragma unroll
        for (int e = 0; e < 4; ++e) {
          float dx = F4E(pxv, e) - cx;
          float dyq = F4E(pyv, e) - cy;
          float u = fmaf(dyq, dyq, dx * dx);
          float v = fmaf(u, -0.5f, F4E(Gv, e));
          tt[k * 4 + e] = v; mf = fmaxf(mf, v);
        }
      }
      #pragma unroll
      for (int o = 1; o < 16; o <<= 1) mf = fmaxf(mf, __shfl_xor(mf, o, 64));
      const float mk2 = mf * KCONV;
      float sf = 0.0f;
      #pragma unroll
      for (int i = 0; i < 16; ++i) sf += EXP2F(fmaf(tt[i], KCONV, -mk2));
      #pragma unroll
      for (int o = 1; o < 16; o <<= 1) sf += __shfl_xor(sf, o, 64);
      if (ch == 0) {
        const float f = -(mf + LOG2F(sf) * INV_KC);
        st_coh(Fbuf + c, f + epsla_c);
        if (it == NITER - 1) acc += a_c * f;
      }
      flag_signal(flg + sub, 2 * it + 2);
      flag_waitall(flg, AB_K, 2 * it + 2);
      F_L[(tid >> 5) * 36 + (tid & 31)] = ld_coh(Fbuf + tid);
      __syncthreads();
      #pragma unroll
      for (int k = 0; k < 4; ++k) {
        float4 Fv = F_L4[r * 9 + h * 4 + k];
        Freg[k * 4 + 0] = Fv.x; Freg[k * 4 + 1] = Fv.y;
        Freg[k * 4 + 2] = Fv.z; Freg[k * 4 + 3] = Fv.w;
      }
    }
  } else if (bid < 192) {
    // =================== ot_bb : 8 teams x 8 blocks ===================
    const int img = (bid - 128) >> 3, sub = (bid - 128) & 7;
    const float* pts = pts_all + img * (NPTS * 2);
    unsigned int* flg = flags + (8 + img) * 16;
    float* Fbuf = ws + WS_BBF + img * NPTS;
    float* Gbuf = ws + WS_BBG + img * NPTS;

    if (tid < NPTS) { pxL[tid] = pts[2 * tid]; pyL[tid] = pts[2 * tid + 1]; }
    __syncthreads();

    const int w = tid >> 6, lane = tid & 63;
    const int j0 = sub * 32 + w * 2;               // two targets per wave
    const float pxj0 = pxL[j0], pyj0 = pyL[j0];
    const float pxj1 = pxL[j0 + 1], pyj1 = pyL[j0 + 1];
    float spx[4], spy[4];
    #pragma unroll
    for (int e = 0; e < 4; ++e) { spx[e] = pxL[lane * 4 + e]; spy[e] = pyL[lane * 4 + e]; }
    const int potw = (lane >> 1) * 12 + (lane & 1) * 4;

    for (int it = 0;; ++it) {
      float P[4];
      if (it == 0) { P[0] = P[1] = P[2] = P[3] = EPS_LBC; }
      else { float4 v = *(const float4*)(ALb + potw); P[0] = v.x; P[1] = v.y; P[2] = v.z; P[3] = v.w; }

      float g01[2];
      #pragma unroll
      for (int t = 0; t < 2; ++t) {
        const float qx = t ? pxj1 : pxj0, qy = t ? pyj1 : pyj0;
        float tt0[4]; float m = -INFINITY;
        #pragma unroll
        for (int e = 0; e < 4; ++e) {
          float dx = spx[e] - qx, dyq = spy[e] - qy;
          float u = fmaf(dyq, dyq, dx * dx);
          float v = fmaf(u, -0.5f, P[e]);
          tt0[e] = v; m = fmaxf(m, v);
        }
        #pragma unroll
        for (int o = 1; o < 64; o <<= 1) m = fmaxf(m, __shfl_xor(m, o, 64));
        const float mk = m * KCONV;
        float s = 0.0f;
        #pragma unroll
        for (int e = 0; e < 4; ++e) s += EXP2F(fmaf(tt0[e], KCONV, -mk));
        #pragma unroll
        for (int o = 1; o < 64; o <<= 1) s += __shfl_xor(s, o, 64);
        g01[t] = -(m + LOG2F(s) * INV_KC);
      }
      if (it == NITER) { if (lane == 0) acc += (g01[0] + g01[1]) * (1.0f / 256.0f); break; }
      if (lane == 0) { st_coh(Gbuf + j0, g01[0] + EPS_LBC); st_coh(Gbuf + j0 + 1, g01[1] + EPS_LBC); }
      flag_signal(flg + sub, 2 * it + 1);
      flag_waitall(flg, BB_K, 2 * it + 1);
      if (tid < NPTS) ALb[(tid >> 3) * 12 + (tid & 7)] = ld_coh(Gbuf + tid);
      __syncthreads();

      {
        float4 v = *(const float4*)(ALb + potw);
        P[0] = v.x; P[1] = v.y; P[2] = v.z; P[3] = v.w;
      }
      float f01[2];
      #pragma unroll
      for (int t = 0; t < 2; ++t) {
        const float qx = t ? pxj1 : pxj0, qy = t ? pyj1 : pyj0;
        float tt0[4]; float m = -INFINITY;
        #pragma unroll
        for (int e = 0; e < 4; ++e) {
          float dx = spx[e] - qx, dyq = spy[e] - qy;
          float u = fmaf(dyq, dyq, dx * dx);
          float v = fmaf(u, -0.5f, P[e]);
          tt0[e] = v; m = fmaxf(m, v);
        }
        #pragma unroll
        for (int o = 1; o < 64; o <<= 1) m = fmaxf(m, __shfl_xor(m, o, 64));
        const float mk = m * KCONV;
        float s = 0.0f;
        #pragma unroll
        for (int e = 0; e < 4; ++e) s += EXP2F(fmaf(tt0[e], KCONV, -mk));
        #pragma unroll
        for (int o = 1; o < 64; o <<= 1) s += __shfl_xor(s, o, 64);
        f01[t] = -(m + LOG2F(s) * INV_KC);
      }
      if (lane == 0) {
        st_coh(Fbuf + j0, f01[0] + EPS_LBC); st_coh(Fbuf + j0 + 1, f01[1] + EPS_LBC);
        if (it == NITER - 1) acc += (f01[0] + f01[1]) * (1.0f / 256.0f);
      }
      flag_signal(flg + sub, 2 * it + 2);
      flag_waitall(flg, BB_K, 2 * it + 2);
      if (tid < NPTS) ALb[(tid >> 3) * 12 + (tid & 7)] = ld_coh(Fbuf + tid);
      __syncthreads();
    }
  } else {
    // =================== ot_aa : 1 block, verified diagonal collapse ===================
    const int img = bid - 192;
    const float* dens = dens_all + img * NSRC;
    const float d_np = dens[tid];
    const float a_np = d_np;
    const float epsla_np = (d_np > 0.0f) ? EPSQ * __logf(d_np) : NEG_BIG;
    float myF = epsla_np;                // f = 0 in t-units
    FaL[tid] = myF;
    __syncthreads();

    const int w = tid >> 6, lane = tid & 63;
    const int q1 = tid & 31, r1 = tid >> 5;   // pass1: column q1, output row r1; cell(tid)=(r1,q1)
    const int q2 = q1, r2 = r1;               // pass2: output col q2, row r2 (same thread = same cell)

    auto aa_half = [&]() -> float {
      // column max of FaL from registers (2 rows per wave -> 16 partials -> CM)
      float cp = fmaxf(myF, __shfl_xor(myF, 32, 64));
      if (lane < 32) PM[w * 33 + lane] = cp;
      __syncthreads();
      if (tid < 32) {
        float cm = -INFINITY;
        #pragma unroll
        for (int w2 = 0; w2 < 16; ++w2) cm = fmaxf(cm, PM[w2 * 33 + tid]);
        CM[tid] = cm;
      }
      __syncthreads();
      const float fmx = CM[q1];
      float Tv;
      if (__all(fmx - 32.0f <= myF - 0.25f)) {
        Tv = myF;                      // off-diagonal terms underflow exactly in fp32
      } else {
        float tv[32]; float m = -INFINITY; float d = (float)(-r1);
        #pragma unroll
        for (int rr = 0; rr < 32; ++rr) {
          float v = fmaf(d * d, -32.0f, FaL[rr * 32 + q1]);
          tv[rr] = v; m = fmaxf(m, v); d += 1.0f;
        }
        const float mk = m * KCONV; float s = 0.0f;
        #pragma unroll
        for (int rr = 0; rr < 32; ++rr) s += EXP2F(fmaf(tv[rr], KCONV, -mk));
        Tv = m + LOG2F(s) * INV_KC;
      }
      TaL[q1 * 33 + r1] = Tv;
      __syncthreads();
      // row max of T over q (lanes of a half-wave hold all q for this r)
      float tmx = Tv;
      #pragma unroll
      for (int o = 1; o < 32; o <<= 1) tmx = fmaxf(tmx, __shfl_xor(tmx, o, 64));
      float outv;
      if (__all(tmx - 32.0f <= Tv - 0.25f)) {
        outv = Tv;
      } else {
        float tv[32]; float m = -INFINITY; float d = (float)(-q2);
        #pragma unroll
        for (int qi = 0; qi < 32; ++qi) {
          float v = fmaf(d * d, -32.0f, TaL[qi * 33 + r2]);
          tv[qi] = v; m = fmaxf(m, v); d += 1.0f;
        }
        const float mk = m * KCONV; float s = 0.0f;
        #pragma unroll
        for (int qi = 0; qi < 32; ++qi) s += EXP2F(fmaf(tv[qi], KCONV, -mk));
        outv = m + LOG2F(s) * INV_KC;
      }
      return -outv;
    };

    for (int it = 0;; ++it) {
      float gpot = aa_half();
      if (it == NITER) { acc += a_np * gpot; break; }
      myF = gpot + epsla_np; FaL[tid] = myF;
      __syncthreads();
      float fpot = aa_half();
      if (it == NITER - 1) acc += a_np * fpot;
      myF = fpot + epsla_np; FaL[tid] = myF;
      __syncthreads();
    }
  }

  // ---- block reduction + per-block partial ----
  {
    #pragma unroll
    for (int o = 32; o; o >>= 1) acc += __shfl_xor(acc, o, 64);
    __syncthreads();
    if ((tid & 63) == 0) red[tid >> 6] = acc;
    __syncthreads();
    if (tid == 0) {
      float tsum = 0.0f;
      #pragma unroll
      for (int k = 0; k < 16; ++k) tsum += red[k];
      partials[bid] = tsum;
    }
  }
}

__global__ void ot_finalize(const float* __restrict__ partials, float* __restrict__ out) {
  __shared__ float red[4];
  const int tid = threadIdx.x;
  float v = 0.0f;
  if (tid < 200) v = ((tid < 128) ? 1.0f : -0.5f) * partials[tid];
  #pragma unroll
  for (int o = 32; o; o >>= 1) v += __shfl_xor(v, o, 64);
  if ((tid & 63) == 0) red[tid >> 6] = v;
  __syncthreads();
  if (tid == 0) out[0] = red[0] + red[1] + red[2] + red[3];
}

extern "C" void kernel_launch(void* const* d_in, const int* in_sizes, int n_in,
                              void* d_out, int out_size, void* d_ws, size_t ws_size,
                              hipStream_t stream) {
  const float* dens = (const float*)d_in[0];   // (8,1,32,32) f32
  const float* pts  = (const float*)d_in[1];   // (8,256,2)   f32
  float* ws = (float*)d_ws;
  (void)hipMemsetAsync(d_ws, 0, WS_MEMSET_BYTES, stream);   // zero the flag region
  ot_sinkhorn<<<dim3(200), dim3(1024), 0, stream>>>(dens, pts, ws);
  ot_finalize<<<dim3(1), dim3(256), 0, stream>>>(ws + WS_PART, (float*)d_out);
}